// Round 11
// baseline (137.245 us; speedup 1.0000x reference)
//
#include <hip/hip_runtime.h>
#include <hip/hip_bf16.h>
#include <math.h>

// Problem constants (fixed by setup_inputs)
#define B_    16
#define C_    256
#define P_    16384          // 128*128
#define K_    101            // num_class + 1
#define S_    17             // B + 1 slots per class
#define V_    1717           // K_ * S_
#define GN_   1792           // V_ padded to 28*64
#define NPQ_  8              // pixel-slice partials (2048 px per slice)
#define TEMP_ 0.07f
#define INV_SQRT_T 3.7796447300922720f   // 1/sqrt(0.07)

typedef __bf16 bf16x8 __attribute__((ext_vector_type(8)));
typedef float f32x4 __attribute__((ext_vector_type(4)));
typedef int   i32x4 __attribute__((ext_vector_type(4)));

__device__ __forceinline__ void atomAddGlb(float* p, float v) {
  __hip_atomic_fetch_add(p, v, __ATOMIC_RELAXED, __HIP_MEMORY_SCOPE_AGENT);
}

// pack fp32 x into one dword: low16 = bf16(hi), high16 = bf16(x - hi). Exact.
__device__ __forceinline__ unsigned packHiLo(float x) {
  const unsigned u = __float_as_uint(x);
  const unsigned h = u & 0xFFFF0000u;
  const unsigned l = __float_as_uint(x - __uint_as_float(h));
  return __builtin_amdgcn_perm(l, u, 0x07060302u);  // [l3,l2,u3,u2]
}

__device__ __forceinline__ unsigned ldsAddr(const void* p) {
  return (unsigned)(size_t)(__attribute__((address_space(3))) const void*)p;
}

// ---------------------------------------------------------------------------
// K1: segmented sums via MFMA; wave-private async-LDS staging.
// R10 evidence: perf invariant to occupancy (R5=R8=R10 ~100us) and VALU (R8
// halved it) -> the 16x64B-segment scattered feature loads congest L2/DRAM.
// Now each wave stages its own 16ch x 64px chunk via global_load_lds
// (4 instr x 4 contiguous 256B segments), double-buffered in its private 8KB
// LDS slice; manual counted s_waitcnt vmcnt(4) keeps the next chunk's DMA in
// flight under compute (never drains to 0 mid-loop).  LDS reads are inline-asm
// ds_read_b128 (compiler can't see them -> no conservative vmcnt(0)), with
// lgkmcnt(0)+sched_barrier before use.  Bank spread: XOR-swizzle the GLOBAL
// source px (px ^= (row&7)<<2), LDS kept linear (guide rule #21); read applies
// the same XOR.  k-slot<->pixel map, A-build, psum layout identical to the
// absmax-0.0 R10 kernel.  Grid 2048 working blocks @ (256,4); +16 histogram.
// ---------------------------------------------------------------------------
__global__ __launch_bounds__(256, 4) void k_segsum(
    const int* __restrict__ labels, const float* __restrict__ feats,
    float* __restrict__ psum, unsigned* __restrict__ counts) {
  __shared__ __align__(16) unsigned char smem[32768];  // 4 waves x 2 bufs x 4KB
  __shared__ unsigned s_cnt[102];
  const int id = blockIdx.x;
  const int tid = threadIdx.x;

  if (id >= 2048) {  // ---- label counts for batch id-2048 ----
    const int b = id - 2048;
    if (tid < 102) s_cnt[tid] = 0u;
    __syncthreads();
    for (int i = 0; i < 64; ++i) {
      int lab = labels[b * P_ + i * 256 + tid];
      if ((unsigned)lab > 100u) lab = 101;
      atomicAdd(&s_cnt[lab], 1u);
    }
    __syncthreads();
    if (tid < K_) counts[b * K_ + tid] = s_cnt[tid];
    return;
  }

  const int cg = id & 15, pqg = (id >> 4) & 7, b = id >> 7;
  const int wv = tid >> 6, ln = tid & 63;
  const int lg = ln >> 4;    // lane group 0..3
  const int lc = ln & 15;    // A row (class) / B col (channel)
  const int pq = pqg * 4 + wv;
  const int pbase = pq * 512;
  const float* fbl = feats + ((size_t)b * C_ + cg * 16) * P_ + pbase;
  const int* lptr = labels + b * P_ + pbase;

  unsigned char* ftw = smem + wv * 8192;     // wave-private: 2 x 4KB buffers
  const unsigned ftw_lds = ldsAddr(ftw);

  f32x4 acc[7];
#pragma unroll
  for (int t = 0; t < 7; ++t) acc[t] = (f32x4)0.f;

  // issue the 4 async loads of chunk ck into buffer q (dest uniform: HW
  // writes lane i at base + i*16B; source is per-lane, px pre-swizzled).
  auto issue = [&](int ck, int q) {
#pragma unroll
    for (int j = 0; j < 4; ++j) {
      const int row = j * 4 + lg;                       // lg == ln>>4
      const int px = (lc * 4) ^ ((row & 7) << 2);       // lc == ln&15
      const float* src = fbl + (size_t)row * P_ + ck * 64 + px;
      __builtin_amdgcn_global_load_lds(
          (const __attribute__((address_space(1))) void*)src,
          (__attribute__((address_space(3))) void*)(ftw + q * 4096 + j * 1024),
          16, 0, 0);
    }
  };

  issue(0, 0);
  int q = 0;
  for (int ck = 0; ck < 8; ++ck) {
    if (ck < 7) {
      issue(ck + 1, q ^ 1);
      asm volatile("s_waitcnt vmcnt(4)" ::: "memory");  // chunk ck arrived
    } else {
      asm volatile("s_waitcnt vmcnt(0)" ::: "memory");
    }
    __builtin_amdgcn_sched_barrier(0);
    // ---- 4 windows of 16 px: batched asm ds_reads, then compute ----
    f32x4 fw0, fw1, fw2, fw3;
    {
      const unsigned base = ftw_lds + (unsigned)(q * 4096) + (unsigned)(lc * 256);
      const unsigned sw = (unsigned)((lc & 7) << 4);    // byte swizzle = s*4
      const unsigned a0 = base + ((unsigned)(0 * 64 + lg * 16) ^ sw);
      const unsigned a1 = base + ((unsigned)(1 * 64 + lg * 16) ^ sw);
      const unsigned a2 = base + ((unsigned)(2 * 64 + lg * 16) ^ sw);
      const unsigned a3 = base + ((unsigned)(3 * 64 + lg * 16) ^ sw);
      asm volatile("ds_read_b128 %0, %1" : "=v"(fw0) : "v"(a0));
      asm volatile("ds_read_b128 %0, %1" : "=v"(fw1) : "v"(a1));
      asm volatile("ds_read_b128 %0, %1" : "=v"(fw2) : "v"(a2));
      asm volatile("ds_read_b128 %0, %1" : "=v"(fw3) : "v"(a3));
      asm volatile("s_waitcnt lgkmcnt(0)" ::: "memory");
      __builtin_amdgcn_sched_barrier(0);
    }
#pragma unroll
    for (int win = 0; win < 4; ++win) {
      const f32x4 f = (win == 0) ? fw0 : (win == 1) ? fw1 : (win == 2) ? fw2 : fw3;
      const i32x4 lv = *(const i32x4*)&lptr[ck * 64 + win * 16 + lg * 4];
      int d[4];
#pragma unroll
      for (int r = 0; r < 4; ++r) d[r] = lv[r] - lc;
      i32x4 pk;
      pk[0] = (int)packHiLo(f[0]); pk[1] = (int)packHiLo(f[1]);
      pk[2] = (int)packHiLo(f[2]); pk[3] = (int)packHiLo(f[3]);
      const bf16x8 bf = __builtin_bit_cast(bf16x8, pk);
#pragma unroll
      for (int t = 0; t < 7; ++t) {
        const int m0 = t * 16;
        i32x4 av;
#pragma unroll
        for (int r = 0; r < 4; ++r)
          av[r] = (d[r] == m0) ? (int)0x3F803F80 : 0;
        acc[t] = __builtin_amdgcn_mfma_f32_16x16x32_bf16(
            __builtin_bit_cast(bf16x8, av), bf, acc[t], 0, 0, 0);
      }
    }
    q ^= 1;
  }
  // ---- block reduce over the 4 waves (LDS reused); wave 0 writes psum ----
  __syncthreads();
  f32x4* s_red = (f32x4*)smem;
  float* pbas = psum + ((size_t)(pqg * 16 + b) * K_) * 256 + cg * 16 + lc;
#pragma unroll
  for (int t = 0; t < 7; ++t) {
    s_red[wv * 64 + ln] = acc[t];
    __syncthreads();
    if (wv == 0) {
      const f32x4 a0 = s_red[ln], a1 = s_red[64 + ln];
      const f32x4 a2 = s_red[128 + ln], a3 = s_red[192 + ln];
#pragma unroll
      for (int r = 0; r < 4; ++r) {
        const int row = t * 16 + lg * 4 + r;
        if (row < K_)
          pbas[(size_t)row * 256] = a0[r] + a1[r] + a2[r] + a3[r];
      }
    }
    __syncthreads();
  }
}

// ---------------------------------------------------------------------------
// K2: normalized prototype slots scaled by 1/sqrt(T); wave-per-slot (4 slots
// concurrent, float4 loads, shfl_xor reduce).  Emits exact bf16 hi/lo planes;
// valid/cnt/wcol/cnt_exist.  grid K_ blocks x 256 thr.
// ---------------------------------------------------------------------------
__global__ __launch_bounds__(256) void k_protos(
    const float* __restrict__ psum, const unsigned* __restrict__ counts,
    const float* __restrict__ prototypes, unsigned short* __restrict__ PmH,
    unsigned short* __restrict__ PmL, int* __restrict__ valid,
    float* __restrict__ wcol, float* __restrict__ cntk,
    float* __restrict__ scal) {
  const int k = blockIdx.x;
  const int tid = threadIdx.x, wv = tid >> 6, ln = tid & 63;
  __shared__ int s_valid[S_];
  for (int s = wv; s < S_; s += 4) {
    float val[4];
    int pres;
    if (s < B_) {
      const unsigned cb = counts[s * K_ + k];
      float4 v = {0.f, 0.f, 0.f, 0.f};
#pragma unroll
      for (int pq = 0; pq < NPQ_; ++pq) {
        const float4 t4 =
            *(const float4*)&psum[((size_t)(pq * 16 + s) * K_ + k) * 256 + ln * 4];
        v.x += t4.x; v.y += t4.y; v.z += t4.z; v.w += t4.w;
      }
      const float cbf = fmaxf((float)cb, 1.f);
      val[0] = v.x / cbf; val[1] = v.y / cbf; val[2] = v.z / cbf; val[3] = v.w / cbf;
      pres = (cb > 0u) && (k >= 1);
    } else {
      const float4 pv4 = *(const float4*)&prototypes[k * C_ + ln * 4];
      val[0] = pv4.x; val[1] = pv4.y; val[2] = pv4.z; val[3] = pv4.w;
      pres = (k >= 1);
    }
    float ss = val[0] * val[0] + val[1] * val[1] + val[2] * val[2] + val[3] * val[3];
#pragma unroll
    for (int m = 1; m < 64; m <<= 1) ss += __shfl_xor(ss, m);
    const float nrm = fmaxf(sqrtf(ss), 1e-12f);
    unsigned short h[4], l[4];
#pragma unroll
    for (int j = 0; j < 4; ++j) {
      const float pv = pres ? (val[j] / nrm) * INV_SQRT_T : 0.f;
      const unsigned u = __float_as_uint(pv);
      const float lo = pv - __uint_as_float(u & 0xFFFF0000u);
      h[j] = (unsigned short)(u >> 16);
      l[j] = (unsigned short)(__float_as_uint(lo) >> 16);
    }
    const size_t idx = ((size_t)k * S_ + s) * C_ + ln * 4;
    *(ushort4*)&PmH[idx] = make_ushort4(h[0], h[1], h[2], h[3]);
    *(ushort4*)&PmL[idx] = make_ushort4(l[0], l[1], l[2], l[3]);
    if (ln == 0) s_valid[s] = pres;
  }
  __syncthreads();
  if (tid == 0) {
    int cnt = 0;
    for (int s = 0; s < S_; ++s) cnt += s_valid[s];
    const float cf = (float)cnt;
    cntk[k] = cf;
    const float wvv = 1.f / fmaxf(cf, 1.f);
    for (int s = 0; s < S_; ++s) {
      valid[k * S_ + s] = s_valid[s];
      wcol[k * S_ + s] = s_valid[s] ? wvv : 0.f;
    }
    if (cnt > 1 && k >= 1) atomAddGlb(&scal[1], 1.f);
  }
}

// ---------------------------------------------------------------------------
// K3: Gram G = Pm*Pm^T via bf16 MFMA with exact hi/lo split:
// G ~= H*H^T + H*L^T + L*H^T   (lo*lo ~ 2^-16 relative, dropped).
// 64x64 tile per wave, 4 waves/block, grid 196 blocks = 784 tiles.
// ---------------------------------------------------------------------------
__global__ __launch_bounds__(256) void k_gram(
    const unsigned short* __restrict__ PmH,
    const unsigned short* __restrict__ PmL, float* __restrict__ G) {
  const int tid = threadIdx.x;
  const int wv = tid >> 6, ln = tid & 63;
  const int gid = blockIdx.x * 4 + wv;       // 0..783
  const int ri = gid / 28, cj = gid % 28;    // 64x64 tile coords
  const int lg = ln >> 4, lc = ln & 15;

  f32x4 acc[4][4];
#pragma unroll
  for (int m = 0; m < 4; ++m)
#pragma unroll
    for (int n = 0; n < 4; ++n) acc[m][n] = (f32x4)0.f;

#pragma unroll
  for (int ks = 0; ks < 8; ++ks) {
    const int kb = ks * 32 + lg * 8;
    bf16x8 aH[4], aL[4], bH[4], bL[4];
#pragma unroll
    for (int m = 0; m < 4; ++m) {
      const size_t ra = (size_t)(ri * 64 + m * 16 + lc) * C_ + kb;
      aH[m] = __builtin_bit_cast(bf16x8, *(const i32x4*)&PmH[ra]);
      aL[m] = __builtin_bit_cast(bf16x8, *(const i32x4*)&PmL[ra]);
      const size_t rb = (size_t)(cj * 64 + m * 16 + lc) * C_ + kb;
      bH[m] = __builtin_bit_cast(bf16x8, *(const i32x4*)&PmH[rb]);
      bL[m] = __builtin_bit_cast(bf16x8, *(const i32x4*)&PmL[rb]);
    }
#pragma unroll
    for (int m = 0; m < 4; ++m)
#pragma unroll
      for (int n = 0; n < 4; ++n) {
        acc[m][n] = __builtin_amdgcn_mfma_f32_16x16x32_bf16(aH[m], bH[n], acc[m][n], 0, 0, 0);
        acc[m][n] = __builtin_amdgcn_mfma_f32_16x16x32_bf16(aH[m], bL[n], acc[m][n], 0, 0, 0);
        acc[m][n] = __builtin_amdgcn_mfma_f32_16x16x32_bf16(aL[m], bH[n], acc[m][n], 0, 0, 0);
      }
  }
  // D: row = m*16 + lg*4 + r, col = n*16 + lc
#pragma unroll
  for (int m = 0; m < 4; ++m)
#pragma unroll
    for (int r = 0; r < 4; ++r) {
      float* gr = &G[(size_t)(ri * 64 + m * 16 + lg * 4 + r) * GN_ + cj * 64 + lc];
#pragma unroll
      for (int n = 0; n < 4; ++n) gr[n * 16] = acc[m][n][r];
    }
}

// ---------------------------------------------------------------------------
// K4: per-anchor loss. grid (16 slots, 101 classes), block 256.
// ---------------------------------------------------------------------------
__global__ __launch_bounds__(256) void k_loss(
    const float* __restrict__ G, const int* __restrict__ valid,
    const float* __restrict__ wcol, const float* __restrict__ cntk,
    float* __restrict__ scal) {
  const int s = blockIdx.x;  // 0..15 (batch slots only = anchors)
  const int k = blockIdx.y;  // 0..100
  const int a = k * S_ + s;
  if (!valid[a]) return;  // uniform over block
  const int tid = threadIdx.x;
  const float* row = G + (size_t)a * GN_;
  float dpart = 0.f;
  for (int j = tid; j < GN_; j += 256) dpart += wcol[j] * __expf(row[j]);
  __shared__ float red[4];
#pragma unroll
  for (int o = 32; o > 0; o >>= 1) dpart += __shfl_down(dpart, o);
  if ((tid & 63) == 0) red[tid >> 6] = dpart;
  __syncthreads();
  if (tid == 0) {
    const float den = red[0] + red[1] + red[2] + red[3];
    float pos = 0.f;
    for (int n = 0; n < S_; ++n)
      if (valid[k * S_ + n]) pos += row[k * S_ + n];
    pos -= row[a];  // remove self term (diag)
    const float np = cntk[k] - 1.f;
    const float npc = fmaxf(np, 1.f);
    const float pa = -(pos - np * logf(den)) / (npc * npc);
    atomAddGlb(&scal[0], pa);
  }
}

__global__ void k_final(const float* __restrict__ scal, float* __restrict__ out) {
  out[0] = 0.1f * scal[0] / scal[1];
}

// ---------------------------------------------------------------------------
extern "C" void kernel_launch(void* const* d_in, const int* in_sizes, int n_in,
                              void* d_out, int out_size, void* d_ws, size_t ws_size,
                              hipStream_t stream) {
  const int* labels = (const int*)d_in[0];
  const float* feats = (const float*)d_in[1];
  const float* protos = (const float*)d_in[2];
  float* out = (float*)d_out;

  char* wsb = (char*)d_ws;
  size_t o = 0;
  auto nxt = [&](size_t bytes) {
    size_t r = o;
    o = (o + bytes + 255) & ~(size_t)255;
    return r;
  };
  // Small region (memset each call):
  const size_t off_cnts = nxt((size_t)B_ * K_ * 4);
  const size_t off_PH   = nxt((size_t)GN_ * C_ * 2);
  const size_t off_PL   = nxt((size_t)GN_ * C_ * 2);
  const size_t off_val  = nxt((size_t)GN_ * 4);
  const size_t off_w    = nxt((size_t)GN_ * 4);
  const size_t off_cntk = nxt((size_t)K_ * 4);
  const size_t off_scal = nxt(8);
  const size_t small_end = o;
  // Big region: psum partials and G share storage (disjoint lifetimes).
  const size_t psum_bytes = (size_t)NPQ_ * 16 * K_ * 256 * 4;  // 13.2 MB
  const size_t g_bytes = (size_t)GN_ * GN_ * 4;                // 12.8 MB
  const size_t off_big = nxt(psum_bytes > g_bytes ? psum_bytes : g_bytes);

  unsigned* w_cnts = (unsigned*)(wsb + off_cnts);
  unsigned short* w_PH = (unsigned short*)(wsb + off_PH);
  unsigned short* w_PL = (unsigned short*)(wsb + off_PL);
  int* w_valid     = (int*)(wsb + off_val);
  float* w_w       = (float*)(wsb + off_w);
  float* w_cntk    = (float*)(wsb + off_cntk);
  float* w_scal    = (float*)(wsb + off_scal);
  float* w_psum    = (float*)(wsb + off_big);
  float* w_G       = (float*)(wsb + off_big);

  // Zero the small region (PmH/PmL pad rows feed k_gram; scalars accumulate).
  hipMemsetAsync(d_ws, 0, small_end, stream);

  k_segsum<<<2064, 256, 0, stream>>>(labels, feats, w_psum, w_cnts);
  k_protos<<<K_, 256, 0, stream>>>(w_psum, w_cnts, protos, w_PH, w_PL, w_valid,
                                   w_w, w_cntk, w_scal);
  k_gram<<<196, 256, 0, stream>>>(w_PH, w_PL, w_G);
  k_loss<<<dim3(B_, K_), 256, 0, stream>>>(w_G, w_valid, w_w, w_cntk, w_scal);
  k_final<<<1, 1, 0, stream>>>(w_scal, out);
}

// Round 12
// 135.633 us; speedup vs baseline: 1.0119x; 1.0119x over previous
//
#include <hip/hip_runtime.h>
#include <hip/hip_bf16.h>
#include <math.h>

// Problem constants (fixed by setup_inputs)
#define B_    16
#define C_    256
#define P_    16384          // 128*128
#define K_    101            // num_class + 1
#define S_    17             // B + 1 slots per class
#define V_    1717           // K_ * S_
#define GN_   1792           // V_ padded to 28*64
#define NPQ_  4              // pixel-slice partials (4096 px per slice)
#define TEMP_ 0.07f
#define INV_SQRT_T 3.7796447300922720f   // 1/sqrt(0.07)

typedef __bf16 bf16x8 __attribute__((ext_vector_type(8)));
typedef float f32x4 __attribute__((ext_vector_type(4)));
typedef int   i32x4 __attribute__((ext_vector_type(4)));

__device__ __forceinline__ void atomAddGlb(float* p, float v) {
  __hip_atomic_fetch_add(p, v, __ATOMIC_RELAXED, __HIP_MEMORY_SCOPE_AGENT);
}

// pack fp32 x into one dword: low16 = bf16(hi), high16 = bf16(x - hi). Exact.
__device__ __forceinline__ unsigned packHiLo(float x) {
  const unsigned u = __float_as_uint(x);
  const unsigned h = u & 0xFFFF0000u;
  const unsigned l = __float_as_uint(x - __uint_as_float(h));
  return __builtin_amdgcn_perm(l, u, 0x07060302u);  // [l3,l2,u3,u2]
}

// ---------------------------------------------------------------------------
// K1: segmented sums via MFMA -- ONE sequential DRAM stream per wave.
// R8-R11 invariance (occupancy, VALU, burst width, pipelining all no-ops)
// points at concurrent-stream count: 16 strided row-streams per wave ~ 32K
// device-wide open DRAM pages -> page thrash caps ~3TB/s.  Now each of the 16
// waves in a 1024-thr block streams ITS OWN channel row sequentially (float4
// per lane, 1KB/instr), packs hi|lo bf16, stages to a double-buffered 2x64KB
// LDS tile; compute reads B-frags cross-channel from LDS (XOR-swizzled px,
// same involution both sides).  A-build / k-slot<->pixel map / MFMA identical
// to the absmax-0.0 R10 kernel.  Per quarter: labels loaded FIRST, next
// quarter's features issued SECOND (label waits leave features in flight),
// compute, barrier, pack+write, barrier.  4096 sequential streams device-wide.
// Block epilogue: 16-wave LDS reduce, 7 tiles in one pass -> psum 4 slabs.
// Grid: 1024 working blocks (b 16 x cg 16 x pqg 4) + 16 histogram blocks.
// ---------------------------------------------------------------------------
__global__ __launch_bounds__(1024, 4) void k_segsum(
    const int* __restrict__ labels, const float* __restrict__ feats,
    float* __restrict__ psum, unsigned* __restrict__ counts) {
  __shared__ __align__(16) unsigned char smem[131072];  // 2 x 64KB buffers
  __shared__ unsigned s_cnt[102];
  const int id = blockIdx.x;
  const int tid = threadIdx.x;

  if (id >= 1024) {  // ---- label counts for batch id-1024 ----
    const int b = id - 1024;
    if (tid < 102) s_cnt[tid] = 0u;
    __syncthreads();
    for (int i = 0; i < 16; ++i) {
      int lab = labels[b * P_ + i * 1024 + tid];
      if ((unsigned)lab > 100u) lab = 101;
      atomicAdd(&s_cnt[lab], 1u);
    }
    __syncthreads();
    if (tid < K_) counts[b * K_ + tid] = s_cnt[tid];
    return;
  }

  const int cg = id & 15, pqg = (id >> 4) & 3, b = id >> 6;
  const int wv = tid >> 6, ln = tid & 63;
  const int lg = ln >> 4;    // lane group 0..3
  const int lc = ln & 15;    // A row (class) / B col (channel)
  const int pbase = pqg * 4096;
  // this wave's OWN channel row (sequential stream):
  const float* frow = feats + ((size_t)b * C_ + cg * 16 + wv) * P_ + pbase;
  const int* lbl = labels + b * P_ + pbase;

  unsigned* sm32 = (unsigned*)smem;
  const int mysw = (wv & 7) << 2;    // write-side px swizzle for my row
  const int rdsw = (lc & 7) << 2;    // read-side px swizzle for channel lc

  f32x4 acc[7];
#pragma unroll
  for (int t = 0; t < 7; ++t) acc[t] = (f32x4)0.f;

  // ---- prologue: stage quarter 0 into buffer 0 ----
  {
    float4 f0 = *(const float4*)&frow[0 * 256 + ln * 4];
    float4 f1 = *(const float4*)&frow[1 * 256 + ln * 4];
    float4 f2 = *(const float4*)&frow[2 * 256 + ln * 4];
    float4 f3 = *(const float4*)&frow[3 * 256 + ln * 4];
    const float4 ff[4] = {f0, f1, f2, f3};
#pragma unroll
    for (int i = 0; i < 4; ++i) {
      i32x4 pk;
      pk[0] = (int)packHiLo(ff[i].x); pk[1] = (int)packHiLo(ff[i].y);
      pk[2] = (int)packHiLo(ff[i].z); pk[3] = (int)packHiLo(ff[i].w);
      const int px = (i * 256 + ln * 4) ^ mysw;
      *(i32x4*)&sm32[wv * 1024 + px] = pk;
    }
  }
  __syncthreads();

  for (int q = 0; q < 4; ++q) {
    const int qb = q * 1024;
    const unsigned* bufr = sm32 + (q & 1) * 16384;
    // (1) labels for this wave's 4 windows of quarter q (loaded first)
    i32x4 lv[4];
#pragma unroll
    for (int wi = 0; wi < 4; ++wi)
      lv[wi] = *(const i32x4*)&lbl[qb + (wv * 4 + wi) * 16 + lg * 4];
    // (2) issue next quarter's feature loads (stay in flight under compute)
    float4 nf[4];
    if (q < 3) {
#pragma unroll
      for (int i = 0; i < 4; ++i)
        nf[i] = *(const float4*)&frow[qb + 1024 + i * 256 + ln * 4];
    }
    // (3) compute: 4 windows of 16 px, B-frags from LDS
#pragma unroll
    for (int wi = 0; wi < 4; ++wi) {
      const int win = wv * 4 + wi;
      const int px = (win * 16 + lg * 4) ^ rdsw;
      const bf16x8 bf =
          __builtin_bit_cast(bf16x8, *(const i32x4*)&bufr[lc * 1024 + px]);
      int d[4];
#pragma unroll
      for (int r = 0; r < 4; ++r) d[r] = lv[wi][r] - lc;
#pragma unroll
      for (int t = 0; t < 7; ++t) {
        const int m0 = t * 16;
        i32x4 av;
#pragma unroll
        for (int r = 0; r < 4; ++r)
          av[r] = (d[r] == m0) ? (int)0x3F803F80 : 0;
        acc[t] = __builtin_amdgcn_mfma_f32_16x16x32_bf16(
            __builtin_bit_cast(bf16x8, av), bf, acc[t], 0, 0, 0);
      }
    }
    __syncthreads();  // all readers of buf[(q+1)&1] (prev compute) are done
    // (4) pack + write next quarter into the other buffer
    if (q < 3) {
      unsigned* bufw = sm32 + ((q + 1) & 1) * 16384;
#pragma unroll
      for (int i = 0; i < 4; ++i) {
        i32x4 pk;
        pk[0] = (int)packHiLo(nf[i].x); pk[1] = (int)packHiLo(nf[i].y);
        pk[2] = (int)packHiLo(nf[i].z); pk[3] = (int)packHiLo(nf[i].w);
        const int px = (i * 256 + ln * 4) ^ mysw;
        *(i32x4*)&bufw[wv * 1024 + px] = pk;
      }
    }
    __syncthreads();
  }

  // ---- block reduce over the 16 waves: all 7 tiles in one LDS pass ----
  f32x4* s_red = (f32x4*)smem;       // 7 x 16 x 64 f32x4 = 112KB
#pragma unroll
  for (int t = 0; t < 7; ++t) s_red[(t * 16 + wv) * 64 + ln] = acc[t];
  __syncthreads();
  if (wv < 7) {
    const int t = wv;
    f32x4 s = (f32x4)0.f;
#pragma unroll
    for (int g = 0; g < 16; ++g) {
      const f32x4 v = s_red[(t * 16 + g) * 64 + ln];
      s[0] += v[0]; s[1] += v[1]; s[2] += v[2]; s[3] += v[3];
    }
    float* pbas = psum + ((size_t)(pqg * 16 + b) * K_) * 256 + cg * 16 + lc;
#pragma unroll
    for (int r = 0; r < 4; ++r) {
      const int row = t * 16 + lg * 4 + r;
      if (row < K_) pbas[(size_t)row * 256] = s[r];
    }
  }
}

// ---------------------------------------------------------------------------
// K2: normalized prototype slots scaled by 1/sqrt(T); wave-per-slot (4 slots
// concurrent, float4 loads, shfl_xor reduce).  Emits exact bf16 hi/lo planes;
// valid/cnt/wcol/cnt_exist.  grid K_ blocks x 256 thr.
// ---------------------------------------------------------------------------
__global__ __launch_bounds__(256) void k_protos(
    const float* __restrict__ psum, const unsigned* __restrict__ counts,
    const float* __restrict__ prototypes, unsigned short* __restrict__ PmH,
    unsigned short* __restrict__ PmL, int* __restrict__ valid,
    float* __restrict__ wcol, float* __restrict__ cntk,
    float* __restrict__ scal) {
  const int k = blockIdx.x;
  const int tid = threadIdx.x, wv = tid >> 6, ln = tid & 63;
  __shared__ int s_valid[S_];
  for (int s = wv; s < S_; s += 4) {
    float val[4];
    int pres;
    if (s < B_) {
      const unsigned cb = counts[s * K_ + k];
      float4 v = {0.f, 0.f, 0.f, 0.f};
#pragma unroll
      for (int pq = 0; pq < NPQ_; ++pq) {
        const float4 t4 =
            *(const float4*)&psum[((size_t)(pq * 16 + s) * K_ + k) * 256 + ln * 4];
        v.x += t4.x; v.y += t4.y; v.z += t4.z; v.w += t4.w;
      }
      const float cbf = fmaxf((float)cb, 1.f);
      val[0] = v.x / cbf; val[1] = v.y / cbf; val[2] = v.z / cbf; val[3] = v.w / cbf;
      pres = (cb > 0u) && (k >= 1);
    } else {
      const float4 pv4 = *(const float4*)&prototypes[k * C_ + ln * 4];
      val[0] = pv4.x; val[1] = pv4.y; val[2] = pv4.z; val[3] = pv4.w;
      pres = (k >= 1);
    }
    float ss = val[0] * val[0] + val[1] * val[1] + val[2] * val[2] + val[3] * val[3];
#pragma unroll
    for (int m = 1; m < 64; m <<= 1) ss += __shfl_xor(ss, m);
    const float nrm = fmaxf(sqrtf(ss), 1e-12f);
    unsigned short h[4], l[4];
#pragma unroll
    for (int j = 0; j < 4; ++j) {
      const float pv = pres ? (val[j] / nrm) * INV_SQRT_T : 0.f;
      const unsigned u = __float_as_uint(pv);
      const float lo = pv - __uint_as_float(u & 0xFFFF0000u);
      h[j] = (unsigned short)(u >> 16);
      l[j] = (unsigned short)(__float_as_uint(lo) >> 16);
    }
    const size_t idx = ((size_t)k * S_ + s) * C_ + ln * 4;
    *(ushort4*)&PmH[idx] = make_ushort4(h[0], h[1], h[2], h[3]);
    *(ushort4*)&PmL[idx] = make_ushort4(l[0], l[1], l[2], l[3]);
    if (ln == 0) s_valid[s] = pres;
  }
  __syncthreads();
  if (tid == 0) {
    int cnt = 0;
    for (int s = 0; s < S_; ++s) cnt += s_valid[s];
    const float cf = (float)cnt;
    cntk[k] = cf;
    const float wvv = 1.f / fmaxf(cf, 1.f);
    for (int s = 0; s < S_; ++s) {
      valid[k * S_ + s] = s_valid[s];
      wcol[k * S_ + s] = s_valid[s] ? wvv : 0.f;
    }
    if (cnt > 1 && k >= 1) atomAddGlb(&scal[1], 1.f);
  }
}

// ---------------------------------------------------------------------------
// K3: Gram G = Pm*Pm^T via bf16 MFMA with exact hi/lo split:
// G ~= H*H^T + H*L^T + L*H^T   (lo*lo ~ 2^-16 relative, dropped).
// 64x64 tile per wave, 4 waves/block, grid 196 blocks = 784 tiles.
// ---------------------------------------------------------------------------
__global__ __launch_bounds__(256) void k_gram(
    const unsigned short* __restrict__ PmH,
    const unsigned short* __restrict__ PmL, float* __restrict__ G) {
  const int tid = threadIdx.x;
  const int wv = tid >> 6, ln = tid & 63;
  const int gid = blockIdx.x * 4 + wv;       // 0..783
  const int ri = gid / 28, cj = gid % 28;    // 64x64 tile coords
  const int lg = ln >> 4, lc = ln & 15;

  f32x4 acc[4][4];
#pragma unroll
  for (int m = 0; m < 4; ++m)
#pragma unroll
    for (int n = 0; n < 4; ++n) acc[m][n] = (f32x4)0.f;

#pragma unroll
  for (int ks = 0; ks < 8; ++ks) {
    const int kb = ks * 32 + lg * 8;
    bf16x8 aH[4], aL[4], bH[4], bL[4];
#pragma unroll
    for (int m = 0; m < 4; ++m) {
      const size_t ra = (size_t)(ri * 64 + m * 16 + lc) * C_ + kb;
      aH[m] = __builtin_bit_cast(bf16x8, *(const i32x4*)&PmH[ra]);
      aL[m] = __builtin_bit_cast(bf16x8, *(const i32x4*)&PmL[ra]);
      const size_t rb = (size_t)(cj * 64 + m * 16 + lc) * C_ + kb;
      bH[m] = __builtin_bit_cast(bf16x8, *(const i32x4*)&PmH[rb]);
      bL[m] = __builtin_bit_cast(bf16x8, *(const i32x4*)&PmL[rb]);
    }
#pragma unroll
    for (int m = 0; m < 4; ++m)
#pragma unroll
      for (int n = 0; n < 4; ++n) {
        acc[m][n] = __builtin_amdgcn_mfma_f32_16x16x32_bf16(aH[m], bH[n], acc[m][n], 0, 0, 0);
        acc[m][n] = __builtin_amdgcn_mfma_f32_16x16x32_bf16(aH[m], bL[n], acc[m][n], 0, 0, 0);
        acc[m][n] = __builtin_amdgcn_mfma_f32_16x16x32_bf16(aL[m], bH[n], acc[m][n], 0, 0, 0);
      }
  }
  // D: row = m*16 + lg*4 + r, col = n*16 + lc
#pragma unroll
  for (int m = 0; m < 4; ++m)
#pragma unroll
    for (int r = 0; r < 4; ++r) {
      float* gr = &G[(size_t)(ri * 64 + m * 16 + lg * 4 + r) * GN_ + cj * 64 + lc];
#pragma unroll
      for (int n = 0; n < 4; ++n) gr[n * 16] = acc[m][n][r];
    }
}

// ---------------------------------------------------------------------------
// K4: per-anchor loss. grid (16 slots, 101 classes), block 256.
// ---------------------------------------------------------------------------
__global__ __launch_bounds__(256) void k_loss(
    const float* __restrict__ G, const int* __restrict__ valid,
    const float* __restrict__ wcol, const float* __restrict__ cntk,
    float* __restrict__ scal) {
  const int s = blockIdx.x;  // 0..15 (batch slots only = anchors)
  const int k = blockIdx.y;  // 0..100
  const int a = k * S_ + s;
  if (!valid[a]) return;  // uniform over block
  const int tid = threadIdx.x;
  const float* row = G + (size_t)a * GN_;
  float dpart = 0.f;
  for (int j = tid; j < GN_; j += 256) dpart += wcol[j] * __expf(row[j]);
  __shared__ float red[4];
#pragma unroll
  for (int o = 32; o > 0; o >>= 1) dpart += __shfl_down(dpart, o);
  if ((tid & 63) == 0) red[tid >> 6] = dpart;
  __syncthreads();
  if (tid == 0) {
    const float den = red[0] + red[1] + red[2] + red[3];
    float pos = 0.f;
    for (int n = 0; n < S_; ++n)
      if (valid[k * S_ + n]) pos += row[k * S_ + n];
    pos -= row[a];  // remove self term (diag)
    const float np = cntk[k] - 1.f;
    const float npc = fmaxf(np, 1.f);
    const float pa = -(pos - np * logf(den)) / (npc * npc);
    atomAddGlb(&scal[0], pa);
  }
}

__global__ void k_final(const float* __restrict__ scal, float* __restrict__ out) {
  out[0] = 0.1f * scal[0] / scal[1];
}

// ---------------------------------------------------------------------------
extern "C" void kernel_launch(void* const* d_in, const int* in_sizes, int n_in,
                              void* d_out, int out_size, void* d_ws, size_t ws_size,
                              hipStream_t stream) {
  const int* labels = (const int*)d_in[0];
  const float* feats = (const float*)d_in[1];
  const float* protos = (const float*)d_in[2];
  float* out = (float*)d_out;

  char* wsb = (char*)d_ws;
  size_t o = 0;
  auto nxt = [&](size_t bytes) {
    size_t r = o;
    o = (o + bytes + 255) & ~(size_t)255;
    return r;
  };
  // Small region (memset each call):
  const size_t off_cnts = nxt((size_t)B_ * K_ * 4);
  const size_t off_PH   = nxt((size_t)GN_ * C_ * 2);
  const size_t off_PL   = nxt((size_t)GN_ * C_ * 2);
  const size_t off_val  = nxt((size_t)GN_ * 4);
  const size_t off_w    = nxt((size_t)GN_ * 4);
  const size_t off_cntk = nxt((size_t)K_ * 4);
  const size_t off_scal = nxt(8);
  const size_t small_end = o;
  // Big region: psum partials and G share storage (disjoint lifetimes).
  const size_t psum_bytes = (size_t)NPQ_ * 16 * K_ * 256 * 4;  // 6.6 MB
  const size_t g_bytes = (size_t)GN_ * GN_ * 4;                // 12.8 MB
  const size_t off_big = nxt(psum_bytes > g_bytes ? psum_bytes : g_bytes);

  unsigned* w_cnts = (unsigned*)(wsb + off_cnts);
  unsigned short* w_PH = (unsigned short*)(wsb + off_PH);
  unsigned short* w_PL = (unsigned short*)(wsb + off_PL);
  int* w_valid     = (int*)(wsb + off_val);
  float* w_w       = (float*)(wsb + off_w);
  float* w_cntk    = (float*)(wsb + off_cntk);
  float* w_scal    = (float*)(wsb + off_scal);
  float* w_psum    = (float*)(wsb + off_big);
  float* w_G       = (float*)(wsb + off_big);

  // Zero the small region (PmH/PmL pad rows feed k_gram; scalars accumulate).
  hipMemsetAsync(d_ws, 0, small_end, stream);

  k_segsum<<<1040, 1024, 0, stream>>>(labels, feats, w_psum, w_cnts);
  k_protos<<<K_, 256, 0, stream>>>(w_psum, w_cnts, protos, w_PH, w_PL, w_valid,
                                   w_w, w_cntk, w_scal);
  k_gram<<<196, 256, 0, stream>>>(w_PH, w_PL, w_G);
  k_loss<<<dim3(B_, K_), 256, 0, stream>>>(w_G, w_valid, w_w, w_cntk, w_scal);
  k_final<<<1, 1, 0, stream>>>(w_scal, out);
}

// Round 13
// 97.401 us; speedup vs baseline: 1.4091x; 1.3925x over previous
//
#include <hip/hip_runtime.h>
#include <hip/hip_bf16.h>
#include <math.h>

// Problem constants (fixed by setup_inputs)
#define B_    16
#define C_    256
#define P_    16384          // 128*128
#define K_    101            // num_class + 1
#define S_    17             // B + 1 slots per class
#define V_    1717           // K_ * S_
#define GN_   1792           // V_ padded to 28*64
#define NPQ_  8              // pixel-slice partials (2048 px per slice)
#define TEMP_ 0.07f
#define INV_SQRT_T 3.7796447300922720f   // 1/sqrt(0.07)

typedef __bf16 bf16x8 __attribute__((ext_vector_type(8)));
typedef float f32x4 __attribute__((ext_vector_type(4)));
typedef int   i32x4 __attribute__((ext_vector_type(4)));

__device__ __forceinline__ void atomAddGlb(float* p, float v) {
  __hip_atomic_fetch_add(p, v, __ATOMIC_RELAXED, __HIP_MEMORY_SCOPE_AGENT);
}

// pack fp32 x into one dword: low16 = bf16(hi), high16 = bf16(x - hi). Exact.
__device__ __forceinline__ unsigned packHiLo(float x) {
  const unsigned u = __float_as_uint(x);
  const unsigned h = u & 0xFFFF0000u;
  const unsigned l = __float_as_uint(x - __uint_as_float(h));
  return __builtin_amdgcn_perm(l, u, 0x07060302u);  // [l3,l2,u3,u2]
}

// ---------------------------------------------------------------------------
// K1: segmented sums via MFMA -- exact R8 structure (best measured total).
// Interleaved hi|lo k-packing: pixel p -> k-slots (2p,2p+1), A duplicates the
// onehot across the pair.  32 channels/wave (A-fragments amortized over two
// 16-ch tiles).  Grid 1024 working blocks (b 16 x pqg 8 x cg 8) @ (256,4);
// blocks 1024..1039: per-batch label histogram.  Block epilogue: 4-wave LDS
// reduce, waves 0/1 write one psum slab (13.2 MB total).
// ---------------------------------------------------------------------------
__global__ __launch_bounds__(256, 4) void k_segsum(
    const int* __restrict__ labels, const float* __restrict__ feats,
    float* __restrict__ psum, unsigned* __restrict__ counts) {
  __shared__ unsigned s_cnt[102];
  __shared__ f32x4 s_red[2][256];
  const int id = blockIdx.x;
  const int tid = threadIdx.x;

  if (id >= 1024) {  // ---- label counts for batch id-1024 ----
    const int b = id - 1024;
    if (tid < 102) s_cnt[tid] = 0u;
    __syncthreads();
    for (int i = 0; i < 64; ++i) {
      int lab = labels[b * P_ + i * 256 + tid];
      if ((unsigned)lab > 100u) lab = 101;
      atomicAdd(&s_cnt[lab], 1u);
    }
    __syncthreads();
    if (tid < K_) counts[b * K_ + tid] = s_cnt[tid];
    return;
  }

  // cg innermost so the 8 blocks sharing (b,pqg) labels are dispatch-adjacent
  const int cg = id & 7, pqg = (id >> 3) & 7, b = id >> 6;
  const int wv = tid >> 6, ln = tid & 63;
  const int lg = ln >> 4;    // lane group 0..3
  const int lc = ln & 15;    // A row (class) / B col (channel)
  const int pbase = pqg * 2048 + wv * 512;
  const int* lptr = labels + b * P_ + pbase + lg * 4;
  const float* fbase =
      feats + ((size_t)b * C_ + cg * 32 + lc) * P_ + pbase + lg * 4;

  f32x4 acc[2][7];
#pragma unroll
  for (int ct = 0; ct < 2; ++ct)
#pragma unroll
    for (int t = 0; t < 7; ++t) acc[ct][t] = (f32x4)0.f;

  for (int w = 0; w < 16; ++w) {
    const int off = w * 32;
    const i32x4 la0 = *(const i32x4*)&lptr[off];
    const i32x4 la1 = *(const i32x4*)&lptr[off + 16];
    int d0[4], d1[4];
#pragma unroll
    for (int r = 0; r < 4; ++r) { d0[r] = la0[r] - lc; d1[r] = la1[r] - lc; }
    i32x4 p0[2], p1[2];
#pragma unroll
    for (int ct = 0; ct < 2; ++ct) {
      const float4 f0 = *(const float4*)&fbase[(size_t)ct * 16 * P_ + off];
      const float4 f1 = *(const float4*)&fbase[(size_t)ct * 16 * P_ + off + 16];
      p0[ct][0] = (int)packHiLo(f0.x); p0[ct][1] = (int)packHiLo(f0.y);
      p0[ct][2] = (int)packHiLo(f0.z); p0[ct][3] = (int)packHiLo(f0.w);
      p1[ct][0] = (int)packHiLo(f1.x); p1[ct][1] = (int)packHiLo(f1.y);
      p1[ct][2] = (int)packHiLo(f1.z); p1[ct][3] = (int)packHiLo(f1.w);
    }
    const bf16x8 b00 = __builtin_bit_cast(bf16x8, p0[0]);
    const bf16x8 b10 = __builtin_bit_cast(bf16x8, p1[0]);
    const bf16x8 b01 = __builtin_bit_cast(bf16x8, p0[1]);
    const bf16x8 b11 = __builtin_bit_cast(bf16x8, p1[1]);
#pragma unroll
    for (int t = 0; t < 7; ++t) {
      const int m0 = t * 16;
      i32x4 a0v, a1v;
#pragma unroll
      for (int r = 0; r < 4; ++r) {
        a0v[r] = (d0[r] == m0) ? (int)0x3F803F80 : 0;
        a1v[r] = (d1[r] == m0) ? (int)0x3F803F80 : 0;
      }
      const bf16x8 a0 = __builtin_bit_cast(bf16x8, a0v);
      const bf16x8 a1 = __builtin_bit_cast(bf16x8, a1v);
      acc[0][t] = __builtin_amdgcn_mfma_f32_16x16x32_bf16(a0, b00, acc[0][t], 0, 0, 0);
      acc[0][t] = __builtin_amdgcn_mfma_f32_16x16x32_bf16(a1, b10, acc[0][t], 0, 0, 0);
      acc[1][t] = __builtin_amdgcn_mfma_f32_16x16x32_bf16(a0, b01, acc[1][t], 0, 0, 0);
      acc[1][t] = __builtin_amdgcn_mfma_f32_16x16x32_bf16(a1, b11, acc[1][t], 0, 0, 0);
    }
  }
  // ---- block reduce over 4 waves; wave 0 writes chtile 0, wave 1 chtile 1.
  float* pbas = psum + ((size_t)(pqg * 16 + b) * K_) * 256 + cg * 32;
#pragma unroll
  for (int t = 0; t < 7; ++t) {
    s_red[0][wv * 64 + ln] = acc[0][t];
    s_red[1][wv * 64 + ln] = acc[1][t];
    __syncthreads();
    if (wv < 2) {
      const f32x4 a0 = s_red[wv][ln], a1 = s_red[wv][64 + ln];
      const f32x4 a2 = s_red[wv][128 + ln], a3 = s_red[wv][192 + ln];
#pragma unroll
      for (int r = 0; r < 4; ++r) {
        const int row = t * 16 + lg * 4 + r;
        if (row < K_)
          pbas[(size_t)row * 256 + wv * 16 + lc] =
              a0[r] + a1[r] + a2[r] + a3[r];
      }
    }
    __syncthreads();
  }
}

// ---------------------------------------------------------------------------
// K2: normalized prototype slots scaled by 1/sqrt(T); wave-per-slot (4 slots
// concurrent, float4 loads, shfl_xor reduce).  Emits exact bf16 hi/lo planes;
// wcol (valid/cnt folded), cntk, cnt_exist.  grid K_ blocks x 256 thr.
// ---------------------------------------------------------------------------
__global__ __launch_bounds__(256) void k_protos(
    const float* __restrict__ psum, const unsigned* __restrict__ counts,
    const float* __restrict__ prototypes, unsigned short* __restrict__ PmH,
    unsigned short* __restrict__ PmL, float* __restrict__ wcol,
    float* __restrict__ cntk, float* __restrict__ scal) {
  const int k = blockIdx.x;
  const int tid = threadIdx.x, wv = tid >> 6, ln = tid & 63;
  __shared__ int s_valid[S_];
  for (int s = wv; s < S_; s += 4) {
    float val[4];
    int pres;
    if (s < B_) {
      const unsigned cb = counts[s * K_ + k];
      float4 v = {0.f, 0.f, 0.f, 0.f};
#pragma unroll
      for (int pq = 0; pq < NPQ_; ++pq) {
        const float4 t4 =
            *(const float4*)&psum[((size_t)(pq * 16 + s) * K_ + k) * 256 + ln * 4];
        v.x += t4.x; v.y += t4.y; v.z += t4.z; v.w += t4.w;
      }
      const float cbf = fmaxf((float)cb, 1.f);
      val[0] = v.x / cbf; val[1] = v.y / cbf; val[2] = v.z / cbf; val[3] = v.w / cbf;
      pres = (cb > 0u) && (k >= 1);
    } else {
      const float4 pv4 = *(const float4*)&prototypes[k * C_ + ln * 4];
      val[0] = pv4.x; val[1] = pv4.y; val[2] = pv4.z; val[3] = pv4.w;
      pres = (k >= 1);
    }
    float ss = val[0] * val[0] + val[1] * val[1] + val[2] * val[2] + val[3] * val[3];
#pragma unroll
    for (int m = 1; m < 64; m <<= 1) ss += __shfl_xor(ss, m);
    const float nrm = fmaxf(sqrtf(ss), 1e-12f);
    unsigned short h[4], l[4];
#pragma unroll
    for (int j = 0; j < 4; ++j) {
      const float pv = pres ? (val[j] / nrm) * INV_SQRT_T : 0.f;
      const unsigned u = __float_as_uint(pv);
      const float lo = pv - __uint_as_float(u & 0xFFFF0000u);
      h[j] = (unsigned short)(u >> 16);
      l[j] = (unsigned short)(__float_as_uint(lo) >> 16);
    }
    const size_t idx = ((size_t)k * S_ + s) * C_ + ln * 4;
    *(ushort4*)&PmH[idx] = make_ushort4(h[0], h[1], h[2], h[3]);
    *(ushort4*)&PmL[idx] = make_ushort4(l[0], l[1], l[2], l[3]);
    if (ln == 0) s_valid[s] = pres;
  }
  __syncthreads();
  if (tid == 0) {
    int cnt = 0;
    for (int s = 0; s < S_; ++s) cnt += s_valid[s];
    const float cf = (float)cnt;
    cntk[k] = cf;
    const float wvv = 1.f / fmaxf(cf, 1.f);
    for (int s = 0; s < S_; ++s)
      wcol[k * S_ + s] = s_valid[s] ? wvv : 0.f;
    if (cnt > 1 && k >= 1) atomAddGlb(&scal[1], 1.f);
  }
}

// ---------------------------------------------------------------------------
// K3: FUSED gram + loss partials.  G never materialized: each wave computes
// its 64x64 tile of G = Pm*Pm^T (bf16 hi/lo MFMA, exact split, lo*lo dropped)
// in-register, then accumulates per-row
//   den[r] += sum_col wcol[col] * exp(G[r][col])
//   pos[r] += sum_{col: same class, valid, col!=r} G[r][col]
// via 16-lane xor-reduce + ~100K well-spread agent atomics.
// Saves the 26MB G write+read of R12 and the 1616-block k_loss launch.
// grid 196 blocks x 256 thr = 784 tiles.
// ---------------------------------------------------------------------------
__global__ __launch_bounds__(256) void k_gramloss(
    const unsigned short* __restrict__ PmH,
    const unsigned short* __restrict__ PmL, const float* __restrict__ wcol,
    float* __restrict__ den, float* __restrict__ pos) {
  const int tid = threadIdx.x;
  const int wv = tid >> 6, ln = tid & 63;
  const int gid = blockIdx.x * 4 + wv;       // 0..783
  const int ri = gid / 28, cj = gid % 28;    // 64x64 tile coords
  const int lg = ln >> 4, lc = ln & 15;

  f32x4 acc[4][4];
#pragma unroll
  for (int m = 0; m < 4; ++m)
#pragma unroll
    for (int n = 0; n < 4; ++n) acc[m][n] = (f32x4)0.f;

#pragma unroll
  for (int ks = 0; ks < 8; ++ks) {
    const int kb = ks * 32 + lg * 8;
    bf16x8 aH[4], aL[4], bH[4], bL[4];
#pragma unroll
    for (int m = 0; m < 4; ++m) {
      const size_t ra = (size_t)(ri * 64 + m * 16 + lc) * C_ + kb;
      aH[m] = __builtin_bit_cast(bf16x8, *(const i32x4*)&PmH[ra]);
      aL[m] = __builtin_bit_cast(bf16x8, *(const i32x4*)&PmL[ra]);
      const size_t rb = (size_t)(cj * 64 + m * 16 + lc) * C_ + kb;
      bH[m] = __builtin_bit_cast(bf16x8, *(const i32x4*)&PmH[rb]);
      bL[m] = __builtin_bit_cast(bf16x8, *(const i32x4*)&PmL[rb]);
    }
#pragma unroll
    for (int m = 0; m < 4; ++m)
#pragma unroll
      for (int n = 0; n < 4; ++n) {
        acc[m][n] = __builtin_amdgcn_mfma_f32_16x16x32_bf16(aH[m], bH[n], acc[m][n], 0, 0, 0);
        acc[m][n] = __builtin_amdgcn_mfma_f32_16x16x32_bf16(aH[m], bL[n], acc[m][n], 0, 0, 0);
        acc[m][n] = __builtin_amdgcn_mfma_f32_16x16x32_bf16(aL[m], bH[n], acc[m][n], 0, 0, 0);
      }
  }
  // ---- fused loss partials.  G[row][col]: row = ri*64+m*16+lg*4+r,
  // col = cj*64+n*16+lc (this lane's 4 cols).
  float wc[4];
  int cabs[4], ccls[4];
#pragma unroll
  for (int n = 0; n < 4; ++n) {
    cabs[n] = cj * 64 + n * 16 + lc;
    wc[n] = (cabs[n] < V_) ? wcol[cabs[n]] : 0.f;
    ccls[n] = cabs[n] / S_;
  }
  f32x4 denP[4], posP[4];
#pragma unroll
  for (int m = 0; m < 4; ++m) {
    denP[m] = (f32x4)0.f;
    posP[m] = (f32x4)0.f;
    const int rbase = ri * 64 + m * 16 + lg * 4;
#pragma unroll
    for (int r = 0; r < 4; ++r) {
      const int rabs = rbase + r;
      const int rcls = rabs / S_;
#pragma unroll
      for (int n = 0; n < 4; ++n) {
        const float g = acc[m][n][r];
        denP[m][r] += wc[n] * __expf(g);
        if (ccls[n] == rcls && wc[n] > 0.f && cabs[n] != rabs)
          posP[m][r] += g;
      }
    }
  }
  // xor-reduce over the 16 lanes of this lg group (masks 1,2,4,8 stay in-group)
#pragma unroll
  for (int msk = 1; msk <= 8; msk <<= 1)
#pragma unroll
    for (int m = 0; m < 4; ++m)
#pragma unroll
      for (int r = 0; r < 4; ++r) {
        denP[m][r] += __shfl_xor(denP[m][r], msk);
        posP[m][r] += __shfl_xor(posP[m][r], msk);
      }
  if (lc == 0) {
#pragma unroll
    for (int m = 0; m < 4; ++m)
#pragma unroll
      for (int r = 0; r < 4; ++r) {
        const int rabs = ri * 64 + m * 16 + lg * 4 + r;
        if (rabs < V_) {
          atomAddGlb(&den[rabs], denP[m][r]);
          atomAddGlb(&pos[rabs], posP[m][r]);
        }
      }
  }
}

// ---------------------------------------------------------------------------
// K4: finalize.  One block: per-anchor loss from den/pos, block-reduce, write.
// ---------------------------------------------------------------------------
__global__ __launch_bounds__(1024) void k_final(
    const float* __restrict__ den, const float* __restrict__ pos,
    const float* __restrict__ wcol, const float* __restrict__ cntk,
    const float* __restrict__ scal, float* __restrict__ out) {
  const int tid = threadIdx.x;
  float tot = 0.f;
  for (int a = tid; a < V_; a += 1024) {
    const int k = a / S_, s = a - k * S_;
    if (s >= B_ || k < 1 || wcol[a] <= 0.f) continue;
    const float np = cntk[k] - 1.f;
    const float npc = fmaxf(np, 1.f);
    tot += -(pos[a] - np * logf(den[a])) / (npc * npc);
  }
#pragma unroll
  for (int m = 1; m < 64; m <<= 1) tot += __shfl_xor(tot, m);
  __shared__ float red[16];
  if ((tid & 63) == 0) red[tid >> 6] = tot;
  __syncthreads();
  if (tid == 0) {
    float t = 0.f;
#pragma unroll
    for (int i = 0; i < 16; ++i) t += red[i];
    out[0] = 0.1f * t / scal[1];
  }
}

// ---------------------------------------------------------------------------
extern "C" void kernel_launch(void* const* d_in, const int* in_sizes, int n_in,
                              void* d_out, int out_size, void* d_ws, size_t ws_size,
                              hipStream_t stream) {
  const int* labels = (const int*)d_in[0];
  const float* feats = (const float*)d_in[1];
  const float* protos = (const float*)d_in[2];
  float* out = (float*)d_out;

  char* wsb = (char*)d_ws;
  size_t o = 0;
  auto nxt = [&](size_t bytes) {
    size_t r = o;
    o = (o + bytes + 255) & ~(size_t)255;
    return r;
  };
  // Small region (memset each call):
  const size_t off_cnts = nxt((size_t)B_ * K_ * 4);
  const size_t off_PH   = nxt((size_t)GN_ * C_ * 2);
  const size_t off_PL   = nxt((size_t)GN_ * C_ * 2);
  const size_t off_w    = nxt((size_t)GN_ * 4);
  const size_t off_cntk = nxt((size_t)K_ * 4);
  const size_t off_scal = nxt(8);
  const size_t off_den  = nxt((size_t)V_ * 4);
  const size_t off_pos  = nxt((size_t)V_ * 4);
  const size_t small_end = o;
  // Big region: psum partials only (G is never materialized).
  const size_t off_psum = nxt((size_t)NPQ_ * 16 * K_ * 256 * 4);  // 13.2 MB
  (void)off_psum;

  unsigned* w_cnts = (unsigned*)(wsb + off_cnts);
  unsigned short* w_PH = (unsigned short*)(wsb + off_PH);
  unsigned short* w_PL = (unsigned short*)(wsb + off_PL);
  float* w_w       = (float*)(wsb + off_w);
  float* w_cntk    = (float*)(wsb + off_cntk);
  float* w_scal    = (float*)(wsb + off_scal);
  float* w_den     = (float*)(wsb + off_den);
  float* w_pos     = (float*)(wsb + off_pos);
  float* w_psum    = (float*)(wsb + off_psum);

  // Zero the small region (PmH/PmL pads, wcol pads, scal, den/pos accums).
  hipMemsetAsync(d_ws, 0, small_end, stream);

  k_segsum<<<1040, 256, 0, stream>>>(labels, feats, w_psum, w_cnts);
  k_protos<<<K_, 256, 0, stream>>>(w_psum, w_cnts, protos, w_PH, w_PL,
                                   w_w, w_cntk, w_scal);
  k_gramloss<<<196, 256, 0, stream>>>(w_PH, w_PL, w_w, w_den, w_pos);
  k_final<<<1, 1024, 0, stream>>>(w_den, w_pos, w_w, w_cntk, w_scal, out);
}

// Round 14
// 87.561 us; speedup vs baseline: 1.5674x; 1.1124x over previous
//
#include <hip/hip_runtime.h>
#include <hip/hip_bf16.h>
#include <math.h>

// Problem constants (fixed by setup_inputs)
#define B_    16
#define C_    256
#define P_    16384          // 128*128
#define K_    101            // num_class + 1
#define S_    17             // B + 1 slots per class
#define V_    1717           // K_ * S_
#define GN_   1792           // V_ padded to 28*64
#define NPQ_  4              // pixel-slice partials (4096 px per slice)
#define TEMP_ 0.07f
#define INV_SQRT_T 3.7796447300922720f   // 1/sqrt(0.07)

typedef __bf16 bf16x8 __attribute__((ext_vector_type(8)));
typedef float f32x4 __attribute__((ext_vector_type(4)));
typedef int   i32x4 __attribute__((ext_vector_type(4)));

__device__ __forceinline__ void atomAddGlb(float* p, float v) {
  __hip_atomic_fetch_add(p, v, __ATOMIC_RELAXED, __HIP_MEMORY_SCOPE_AGENT);
}

// pack fp32 x into one dword: low16 = bf16(hi), high16 = bf16(x - hi). Exact.
__device__ __forceinline__ unsigned packHiLo(float x) {
  const unsigned u = __float_as_uint(x);
  const unsigned h = u & 0xFFFF0000u;
  const unsigned l = __float_as_uint(x - __uint_as_float(h));
  return __builtin_amdgcn_perm(l, u, 0x07060302u);  // [l3,l2,u3,u2]
}

// ---------------------------------------------------------------------------
// K1: segmented sums via MFMA -- R8/R13 per-wave body (best measured), now in
// 512-thr blocks (8 waves) so one block covers 4096 px -> NPQ 8->4, halving
// the psum round-trip (13.2->6.6 MB each way).  Interleaved hi|lo k-packing:
// pixel p -> k-slots (2p,2p+1), A duplicates the onehot across the pair.
// 32 channels/wave (A-fragments amortized over two 16-ch tiles).
// Grid 512 working blocks (b 16 x pqg 4 x cg 8) @ (512,4) = 16 waves/CU;
// blocks 512..527: per-batch label histogram.  Block epilogue: 8-wave LDS
// reduce, waves 0/1 write one psum slab.
// ---------------------------------------------------------------------------
__global__ __launch_bounds__(512, 4) void k_segsum(
    const int* __restrict__ labels, const float* __restrict__ feats,
    float* __restrict__ psum, unsigned* __restrict__ counts) {
  __shared__ unsigned s_cnt[102];
  __shared__ f32x4 s_red[2][512];
  const int id = blockIdx.x;
  const int tid = threadIdx.x;

  if (id >= 512) {  // ---- label counts for batch id-512 ----
    const int b = id - 512;
    if (tid < 102) s_cnt[tid] = 0u;
    __syncthreads();
    for (int i = 0; i < 32; ++i) {
      int lab = labels[b * P_ + i * 512 + tid];
      if ((unsigned)lab > 100u) lab = 101;
      atomicAdd(&s_cnt[lab], 1u);
    }
    __syncthreads();
    if (tid < K_) counts[b * K_ + tid] = s_cnt[tid];
    return;
  }

  // cg innermost so the 8 blocks sharing (b,pqg) labels are dispatch-adjacent
  const int cg = id & 7, pqg = (id >> 3) & 3, b = id >> 5;
  const int wv = tid >> 6, ln = tid & 63;
  const int lg = ln >> 4;    // lane group 0..3
  const int lc = ln & 15;    // A row (class) / B col (channel)
  const int pq = pqg * 8 + wv;               // 0..31
  const int pbase = pq * 512;
  const int* lptr = labels + b * P_ + pbase + lg * 4;
  const float* fbase =
      feats + ((size_t)b * C_ + cg * 32 + lc) * P_ + pbase + lg * 4;

  f32x4 acc[2][7];
#pragma unroll
  for (int ct = 0; ct < 2; ++ct)
#pragma unroll
    for (int t = 0; t < 7; ++t) acc[ct][t] = (f32x4)0.f;

  for (int w = 0; w < 16; ++w) {
    const int off = w * 32;
    const i32x4 la0 = *(const i32x4*)&lptr[off];
    const i32x4 la1 = *(const i32x4*)&lptr[off + 16];
    int d0[4], d1[4];
#pragma unroll
    for (int r = 0; r < 4; ++r) { d0[r] = la0[r] - lc; d1[r] = la1[r] - lc; }
    i32x4 p0[2], p1[2];
#pragma unroll
    for (int ct = 0; ct < 2; ++ct) {
      const float4 f0 = *(const float4*)&fbase[(size_t)ct * 16 * P_ + off];
      const float4 f1 = *(const float4*)&fbase[(size_t)ct * 16 * P_ + off + 16];
      p0[ct][0] = (int)packHiLo(f0.x); p0[ct][1] = (int)packHiLo(f0.y);
      p0[ct][2] = (int)packHiLo(f0.z); p0[ct][3] = (int)packHiLo(f0.w);
      p1[ct][0] = (int)packHiLo(f1.x); p1[ct][1] = (int)packHiLo(f1.y);
      p1[ct][2] = (int)packHiLo(f1.z); p1[ct][3] = (int)packHiLo(f1.w);
    }
    const bf16x8 b00 = __builtin_bit_cast(bf16x8, p0[0]);
    const bf16x8 b10 = __builtin_bit_cast(bf16x8, p1[0]);
    const bf16x8 b01 = __builtin_bit_cast(bf16x8, p0[1]);
    const bf16x8 b11 = __builtin_bit_cast(bf16x8, p1[1]);
#pragma unroll
    for (int t = 0; t < 7; ++t) {
      const int m0 = t * 16;
      i32x4 a0v, a1v;
#pragma unroll
      for (int r = 0; r < 4; ++r) {
        a0v[r] = (d0[r] == m0) ? (int)0x3F803F80 : 0;
        a1v[r] = (d1[r] == m0) ? (int)0x3F803F80 : 0;
      }
      const bf16x8 a0 = __builtin_bit_cast(bf16x8, a0v);
      const bf16x8 a1 = __builtin_bit_cast(bf16x8, a1v);
      acc[0][t] = __builtin_amdgcn_mfma_f32_16x16x32_bf16(a0, b00, acc[0][t], 0, 0, 0);
      acc[0][t] = __builtin_amdgcn_mfma_f32_16x16x32_bf16(a1, b10, acc[0][t], 0, 0, 0);
      acc[1][t] = __builtin_amdgcn_mfma_f32_16x16x32_bf16(a0, b01, acc[1][t], 0, 0, 0);
      acc[1][t] = __builtin_amdgcn_mfma_f32_16x16x32_bf16(a1, b11, acc[1][t], 0, 0, 0);
    }
  }
  // ---- block reduce over 8 waves; wave 0 writes chtile 0, wave 1 chtile 1.
  float* pbas = psum + ((size_t)(pqg * 16 + b) * K_) * 256 + cg * 32;
#pragma unroll
  for (int t = 0; t < 7; ++t) {
    s_red[0][wv * 64 + ln] = acc[0][t];
    s_red[1][wv * 64 + ln] = acc[1][t];
    __syncthreads();
    if (wv < 2) {
      f32x4 s = (f32x4)0.f;
#pragma unroll
      for (int g = 0; g < 8; ++g) {
        const f32x4 v = s_red[wv][g * 64 + ln];
        s[0] += v[0]; s[1] += v[1]; s[2] += v[2]; s[3] += v[3];
      }
#pragma unroll
      for (int r = 0; r < 4; ++r) {
        const int row = t * 16 + lg * 4 + r;
        if (row < K_)
          pbas[(size_t)row * 256 + wv * 16 + lc] = s[r];
      }
    }
    __syncthreads();
  }
}

// ---------------------------------------------------------------------------
// K2: normalized prototype slots scaled by 1/sqrt(T); 8 waves -> 17 slots in
// 3 rounds, 4 psum slabs per slot (float4 loads, shfl_xor reduce).  Emits
// exact bf16 hi/lo planes; wcol (valid/cnt folded), cntk, cnt_exist.
// grid K_ blocks x 512 thr.
// ---------------------------------------------------------------------------
__global__ __launch_bounds__(512) void k_protos(
    const float* __restrict__ psum, const unsigned* __restrict__ counts,
    const float* __restrict__ prototypes, unsigned short* __restrict__ PmH,
    unsigned short* __restrict__ PmL, float* __restrict__ wcol,
    float* __restrict__ cntk, float* __restrict__ scal) {
  const int k = blockIdx.x;
  const int tid = threadIdx.x, wv = tid >> 6, ln = tid & 63;
  __shared__ int s_valid[S_];
  for (int s = wv; s < S_; s += 8) {
    float val[4];
    int pres;
    if (s < B_) {
      const unsigned cb = counts[s * K_ + k];
      float4 v = {0.f, 0.f, 0.f, 0.f};
#pragma unroll
      for (int pq = 0; pq < NPQ_; ++pq) {
        const float4 t4 =
            *(const float4*)&psum[((size_t)(pq * 16 + s) * K_ + k) * 256 + ln * 4];
        v.x += t4.x; v.y += t4.y; v.z += t4.z; v.w += t4.w;
      }
      const float cbf = fmaxf((float)cb, 1.f);
      val[0] = v.x / cbf; val[1] = v.y / cbf; val[2] = v.z / cbf; val[3] = v.w / cbf;
      pres = (cb > 0u) && (k >= 1);
    } else {
      const float4 pv4 = *(const float4*)&prototypes[k * C_ + ln * 4];
      val[0] = pv4.x; val[1] = pv4.y; val[2] = pv4.z; val[3] = pv4.w;
      pres = (k >= 1);
    }
    float ss = val[0] * val[0] + val[1] * val[1] + val[2] * val[2] + val[3] * val[3];
#pragma unroll
    for (int m = 1; m < 64; m <<= 1) ss += __shfl_xor(ss, m);
    const float nrm = fmaxf(sqrtf(ss), 1e-12f);
    unsigned short h[4], l[4];
#pragma unroll
    for (int j = 0; j < 4; ++j) {
      const float pv = pres ? (val[j] / nrm) * INV_SQRT_T : 0.f;
      const unsigned u = __float_as_uint(pv);
      const float lo = pv - __uint_as_float(u & 0xFFFF0000u);
      h[j] = (unsigned short)(u >> 16);
      l[j] = (unsigned short)(__float_as_uint(lo) >> 16);
    }
    const size_t idx = ((size_t)k * S_ + s) * C_ + ln * 4;
    *(ushort4*)&PmH[idx] = make_ushort4(h[0], h[1], h[2], h[3]);
    *(ushort4*)&PmL[idx] = make_ushort4(l[0], l[1], l[2], l[3]);
    if (ln == 0) s_valid[s] = pres;
  }
  __syncthreads();
  if (tid == 0) {
    int cnt = 0;
    for (int s = 0; s < S_; ++s) cnt += s_valid[s];
    const float cf = (float)cnt;
    cntk[k] = cf;
    const float wvv = 1.f / fmaxf(cf, 1.f);
    for (int s = 0; s < S_; ++s)
      wcol[k * S_ + s] = s_valid[s] ? wvv : 0.f;
    if (cnt > 1 && k >= 1) atomAddGlb(&scal[1], 1.f);
  }
}

// ---------------------------------------------------------------------------
// K3: FUSED gram + loss partials.  G never materialized: each wave computes
// its 64x64 tile of G = Pm*Pm^T (bf16 hi/lo MFMA, exact split, lo*lo dropped)
// in-register, then accumulates per-row
//   den[r] += sum_col wcol[col] * exp(G[r][col])
//   pos[r] += sum_{col: same class, valid, col!=r} G[r][col]
// via 16-lane xor-reduce + well-spread agent atomics.
// grid 196 blocks x 256 thr = 784 tiles.
// ---------------------------------------------------------------------------
__global__ __launch_bounds__(256) void k_gramloss(
    const unsigned short* __restrict__ PmH,
    const unsigned short* __restrict__ PmL, const float* __restrict__ wcol,
    float* __restrict__ den, float* __restrict__ pos) {
  const int tid = threadIdx.x;
  const int wv = tid >> 6, ln = tid & 63;
  const int gid = blockIdx.x * 4 + wv;       // 0..783
  const int ri = gid / 28, cj = gid % 28;    // 64x64 tile coords
  const int lg = ln >> 4, lc = ln & 15;

  f32x4 acc[4][4];
#pragma unroll
  for (int m = 0; m < 4; ++m)
#pragma unroll
    for (int n = 0; n < 4; ++n) acc[m][n] = (f32x4)0.f;

#pragma unroll
  for (int ks = 0; ks < 8; ++ks) {
    const int kb = ks * 32 + lg * 8;
    bf16x8 aH[4], aL[4], bH[4], bL[4];
#pragma unroll
    for (int m = 0; m < 4; ++m) {
      const size_t ra = (size_t)(ri * 64 + m * 16 + lc) * C_ + kb;
      aH[m] = __builtin_bit_cast(bf16x8, *(const i32x4*)&PmH[ra]);
      aL[m] = __builtin_bit_cast(bf16x8, *(const i32x4*)&PmL[ra]);
      const size_t rb = (size_t)(cj * 64 + m * 16 + lc) * C_ + kb;
      bH[m] = __builtin_bit_cast(bf16x8, *(const i32x4*)&PmH[rb]);
      bL[m] = __builtin_bit_cast(bf16x8, *(const i32x4*)&PmL[rb]);
    }
#pragma unroll
    for (int m = 0; m < 4; ++m)
#pragma unroll
      for (int n = 0; n < 4; ++n) {
        acc[m][n] = __builtin_amdgcn_mfma_f32_16x16x32_bf16(aH[m], bH[n], acc[m][n], 0, 0, 0);
        acc[m][n] = __builtin_amdgcn_mfma_f32_16x16x32_bf16(aH[m], bL[n], acc[m][n], 0, 0, 0);
        acc[m][n] = __builtin_amdgcn_mfma_f32_16x16x32_bf16(aL[m], bH[n], acc[m][n], 0, 0, 0);
      }
  }
  // ---- fused loss partials.  G[row][col]: row = ri*64+m*16+lg*4+r,
  // col = cj*64+n*16+lc (this lane's 4 cols).
  float wc[4];
  int cabs[4], ccls[4];
#pragma unroll
  for (int n = 0; n < 4; ++n) {
    cabs[n] = cj * 64 + n * 16 + lc;
    wc[n] = (cabs[n] < V_) ? wcol[cabs[n]] : 0.f;
    ccls[n] = cabs[n] / S_;
  }
  f32x4 denP[4], posP[4];
#pragma unroll
  for (int m = 0; m < 4; ++m) {
    denP[m] = (f32x4)0.f;
    posP[m] = (f32x4)0.f;
    const int rbase = ri * 64 + m * 16 + lg * 4;
#pragma unroll
    for (int r = 0; r < 4; ++r) {
      const int rabs = rbase + r;
      const int rcls = rabs / S_;
#pragma unroll
      for (int n = 0; n < 4; ++n) {
        const float g = acc[m][n][r];
        denP[m][r] += wc[n] * __expf(g);
        if (ccls[n] == rcls && wc[n] > 0.f && cabs[n] != rabs)
          posP[m][r] += g;
      }
    }
  }
  // xor-reduce over the 16 lanes of this lg group (masks 1,2,4,8 stay in-group)
#pragma unroll
  for (int msk = 1; msk <= 8; msk <<= 1)
#pragma unroll
    for (int m = 0; m < 4; ++m)
#pragma unroll
      for (int r = 0; r < 4; ++r) {
        denP[m][r] += __shfl_xor(denP[m][r], msk);
        posP[m][r] += __shfl_xor(posP[m][r], msk);
      }
  if (lc == 0) {
#pragma unroll
    for (int m = 0; m < 4; ++m)
#pragma unroll
      for (int r = 0; r < 4; ++r) {
        const int rabs = ri * 64 + m * 16 + lg * 4 + r;
        if (rabs < V_) {
          atomAddGlb(&den[rabs], denP[m][r]);
          atomAddGlb(&pos[rabs], posP[m][r]);
        }
      }
  }
}

// ---------------------------------------------------------------------------
// K4: finalize.  One block: per-anchor loss from den/pos, block-reduce, write.
// ---------------------------------------------------------------------------
__global__ __launch_bounds__(1024) void k_final(
    const float* __restrict__ den, const float* __restrict__ pos,
    const float* __restrict__ wcol, const float* __restrict__ cntk,
    const float* __restrict__ scal, float* __restrict__ out) {
  const int tid = threadIdx.x;
  float tot = 0.f;
  for (int a = tid; a < V_; a += 1024) {
    const int k = a / S_, s = a - k * S_;
    if (s >= B_ || k < 1 || wcol[a] <= 0.f) continue;
    const float np = cntk[k] - 1.f;
    const float npc = fmaxf(np, 1.f);
    tot += -(pos[a] - np * logf(den[a])) / (npc * npc);
  }
#pragma unroll
  for (int m = 1; m < 64; m <<= 1) tot += __shfl_xor(tot, m);
  __shared__ float red[16];
  if ((tid & 63) == 0) red[tid >> 6] = tot;
  __syncthreads();
  if (tid == 0) {
    float t = 0.f;
#pragma unroll
    for (int i = 0; i < 16; ++i) t += red[i];
    out[0] = 0.1f * t / scal[1];
  }
}

// ---------------------------------------------------------------------------
extern "C" void kernel_launch(void* const* d_in, const int* in_sizes, int n_in,
                              void* d_out, int out_size, void* d_ws, size_t ws_size,
                              hipStream_t stream) {
  const int* labels = (const int*)d_in[0];
  const float* feats = (const float*)d_in[1];
  const float* protos = (const float*)d_in[2];
  float* out = (float*)d_out;

  char* wsb = (char*)d_ws;
  size_t o = 0;
  auto nxt = [&](size_t bytes) {
    size_t r = o;
    o = (o + bytes + 255) & ~(size_t)255;
    return r;
  };
  // Small region (memset each call):
  const size_t off_cnts = nxt((size_t)B_ * K_ * 4);
  const size_t off_PH   = nxt((size_t)GN_ * C_ * 2);
  const size_t off_PL   = nxt((size_t)GN_ * C_ * 2);
  const size_t off_w    = nxt((size_t)GN_ * 4);
  const size_t off_cntk = nxt((size_t)K_ * 4);
  const size_t off_scal = nxt(8);
  const size_t off_den  = nxt((size_t)V_ * 4);
  const size_t off_pos  = nxt((size_t)V_ * 4);
  const size_t small_end = o;
  // Big region: psum partials only (G is never materialized).
  const size_t off_psum = nxt((size_t)NPQ_ * 16 * K_ * 256 * 4);  // 6.6 MB
  (void)off_psum;

  unsigned* w_cnts = (unsigned*)(wsb + off_cnts);
  unsigned short* w_PH = (unsigned short*)(wsb + off_PH);
  unsigned short* w_PL = (unsigned short*)(wsb + off_PL);
  float* w_w       = (float*)(wsb + off_w);
  float* w_cntk    = (float*)(wsb + off_cntk);
  float* w_scal    = (float*)(wsb + off_scal);
  float* w_den     = (float*)(wsb + off_den);
  float* w_pos     = (float*)(wsb + off_pos);
  float* w_psum    = (float*)(wsb + off_psum);

  // Zero the small region (PmH/PmL pads, wcol pads, scal, den/pos accums).
  hipMemsetAsync(d_ws, 0, small_end, stream);

  k_segsum<<<528, 512, 0, stream>>>(labels, feats, w_psum, w_cnts);
  k_protos<<<K_, 512, 0, stream>>>(w_psum, w_cnts, protos, w_PH, w_PL,
                                   w_w, w_cntk, w_scal);
  k_gramloss<<<196, 256, 0, stream>>>(w_PH, w_PL, w_w, w_den, w_pos);
  k_final<<<1, 1024, 0, stream>>>(w_den, w_pos, w_w, w_cntk, w_scal, out);
}